// Round 15
// baseline (425.061 us; speedup 1.0000x reference)
//
#include <hip/hip_runtime.h>
#include <cfloat>

// Problem constants
#define B_   16
#define C_   256
#define HW_  4096      // 64*64
#define N_   65536     // B_*HW_
#define K_   1024

// Output layout (float32, concatenated flat in return order):
//  [0] loss | [1,+16777216) quantized (b c h w) | [16777217] perplexity
//  [16777218,+67108864) encodings (N,K)
#define OUT_QOFF   1
#define OUT_POFF   16777217
#define OUT_EOFF   16777218

typedef __bf16 bf16x8 __attribute__((ext_vector_type(8)));
typedef float  f32x4  __attribute__((ext_vector_type(4)));

// ---------------------------------------------------------------- bf16 split
__device__ inline ushort f2bf(float f) {
    union { float f; unsigned u; } a; a.f = f;
    unsigned u = a.u;
    unsigned r = (u + 0x7fffu + ((u >> 16) & 1u)) >> 16;   // RNE
    return (ushort)r;
}
__device__ inline float bf2f(ushort u) {
    union { float f; unsigned u; } a; a.u = ((unsigned)u) << 16; return a.f;
}

// ------------------------------------- prep: pack e (2-split) + enorm + cnt0
// One block per code k; thread c handles channel c.
// Packed layout per step s in [0,64): s = (k>>5)*2 + (c>>7); within 16384-B
// block: [split(2)][cg(16)][code(32)][ci(8)] bf16.
__global__ __launch_bounds__(256) void k_prep(const float* __restrict__ emb,
                                              char* __restrict__ epk,
                                              float* __restrict__ enorm,
                                              int* __restrict__ counts) {
    const int k = blockIdx.x;
    const int c = threadIdx.x;
    float v = emb[k * C_ + c];
    ushort h = f2bf(v);
    ushort m = f2bf(v - bf2f(h));
    int s  = (k >> 5) * 2 + (c >> 7);
    int cl = c & 127;
    size_t off = (size_t)s * 16384 + (size_t)((cl >> 3) * 512 + (k & 31) * 16 + (cl & 7) * 2);
    *(ushort*)(epk + off)        = h;
    *(ushort*)(epk + off + 8192) = m;
    float sq = v * v;
    __shared__ float red[4];
#pragma unroll
    for (int o = 32; o > 0; o >>= 1) sq += __shfl_down(sq, o);
    if ((c & 63) == 0) red[c >> 6] = sq;
    __syncthreads();
    if (c == 0) {
        enorm[k]  = (red[0] + red[1]) + (red[2] + red[3]);
        counts[k] = 0;
    }
}

// ---------- MFMA argmin GEMM + interleaved enc-zero fill + fused epilogue
// Block: 64 rows x 1024 codes, 4 waves (16 rows each). During step kt each
// wave zeroes its rows' enc slab [kt*32, kt*32+32) (writes hide under the
// main loop -- all 1024 blocks are co-resident, so end-burst writes cannot
// overlap across blocks). Epilogue: scatter the 1.0s, quantized = gathered
// emb row, loss = ||x||^2 + best distance. vmcnt bookkeeping: zero-stores
// issue between STEP(0) [vmcnt(4): waits 2-step-old stores] and STEP(1)
// [vmcnt(6): its target loads are older than the fresh stores].
// 4-product fp32 emulation: ah*Bh + am*Bh + ah*Bm + am*Bm (R6/R11 numerics).
__global__ __launch_bounds__(256, 4) void k_argmin_mfma(const float* __restrict__ x,
                                                        const char* __restrict__ epk,
                                                        const float* __restrict__ enorm,
                                                        const float* __restrict__ emb,
                                                        int* __restrict__ counts,
                                                        float* __restrict__ enc,
                                                        float* __restrict__ outq,
                                                        float* __restrict__ partials) {
    __shared__ __align__(16) char Bs[2][16384];
    __shared__ float En[K_];
    __shared__ int   widx[4][16];
    __shared__ float xn[4][16];

    const int tid  = threadIdx.x;
    const int lane = tid & 63;
    const int wid  = tid >> 6;
    const int l15  = lane & 15;
    const int kg   = lane >> 4;
    const int row0 = blockIdx.x * 64;
    const int cpOff = wid * 1024 + lane * 16;   // wave's copy offset (4KB/wave)

    for (int i = tid; i < K_; i += 256) En[i] = enorm[i];

    // ---- A fragments: row = row0 + wid*16 + l15, k-elems = kg*8+i.
    //      Also accumulate ||x_row||^2 (fp32) and park it in LDS.
    union FU { bf16x8 v; ushort u[8]; };
    FU Ah[8], Am[8];
    {
        const int n  = row0 + wid * 16 + l15;
        const int b  = n >> 12, hw = n & 4095;
        const float* xb = x + (size_t)b * (C_ * HW_) + hw;
        float xs = 0.f;
#pragma unroll
        for (int cb = 0; cb < 8; ++cb) {
#pragma unroll
            for (int i = 0; i < 8; ++i) {
                float v = xb[(cb * 32 + kg * 8 + i) * HW_];
                xs += v * v;
                ushort h = f2bf(v);
                Ah[cb].u[i] = h;
                Am[cb].u[i] = f2bf(v - bf2f(h));
            }
        }
        xs += __shfl_xor(xs, 16);
        xs += __shfl_xor(xs, 32);          // all kg lanes: full row sum
        if (kg == 0) xn[wid][l15] = xs;
    }
    __syncthreads();   // drains vmcnt+lgkmcnt: clean slate for counting

    // ---- stage step 0 (src and dst share the same offset: cpOff+j*4096)
    {
        const char* src = epk + (size_t)cpOff;
        char* dstb = &Bs[0][0] + cpOff;
#pragma unroll
        for (int j = 0; j < 4; ++j) {
            __builtin_amdgcn_global_load_lds(
                (const __attribute__((address_space(1))) void*)(src + j * 4096),
                (__attribute__((address_space(3))) void*)(dstb + j * 4096), 16, 0, 0);
        }
    }

    float best[4] = {FLT_MAX, FLT_MAX, FLT_MAX, FLT_MAX};
    int   bidx[4] = {0, 0, 0, 0};
    const int laneB = kg * 512 + l15 * 16;
    const f32x4 zero = {0.f, 0.f, 0.f, 0.f};
    f32x4 accA, accB;

#define STEP(H, IS_LAST, VMS) do {                                                  \
    if (!(IS_LAST)) {                                                               \
        int sn = 2 * kt + (H) + 1;                                                  \
        const char* src = epk + (size_t)sn * 16384 + (size_t)cpOff;                 \
        char* dstb = &Bs[1 - (H)][0] + cpOff;                                       \
        _Pragma("unroll")                                                           \
        for (int j = 0; j < 4; ++j) {                                               \
            __builtin_amdgcn_global_load_lds(                                       \
                (const __attribute__((address_space(1))) void*)(src + j * 4096),    \
                (__attribute__((address_space(3))) void*)(dstb + j * 4096),         \
                16, 0, 0);                                                          \
        }                                                                           \
        asm volatile("s_waitcnt vmcnt(" VMS ")" ::: "memory");                      \
    } else {                                                                        \
        asm volatile("s_waitcnt vmcnt(0)" ::: "memory");                            \
    }                                                                               \
    __builtin_amdgcn_s_barrier();                                                   \
    asm volatile("" ::: "memory");                                                  \
    {                                                                               \
        const char* bbase = &Bs[(H)][0] + laneB;                                    \
        _Pragma("unroll")                                                           \
        for (int cbl = 0; cbl < 4; ++cbl) {                                         \
            const char* bp = bbase + cbl * 2048;                                    \
            bf16x8 Bh0 = *(const bf16x8*)(bp);                                      \
            bf16x8 Bm0 = *(const bf16x8*)(bp + 8192);                               \
            bf16x8 Bh1 = *(const bf16x8*)(bp + 256);                                \
            bf16x8 Bm1 = *(const bf16x8*)(bp + 8448);                               \
            const bf16x8 ah = Ah[(H) * 4 + cbl].v;                                  \
            const bf16x8 am = Am[(H) * 4 + cbl].v;                                  \
            accA = __builtin_amdgcn_mfma_f32_16x16x32_bf16(ah, Bh0, accA, 0,0,0);   \
            accB = __builtin_amdgcn_mfma_f32_16x16x32_bf16(ah, Bh1, accB, 0,0,0);   \
            accA = __builtin_amdgcn_mfma_f32_16x16x32_bf16(am, Bh0, accA, 0,0,0);   \
            accB = __builtin_amdgcn_mfma_f32_16x16x32_bf16(am, Bh1, accB, 0,0,0);   \
            accA = __builtin_amdgcn_mfma_f32_16x16x32_bf16(ah, Bm0, accA, 0,0,0);   \
            accB = __builtin_amdgcn_mfma_f32_16x16x32_bf16(ah, Bm1, accB, 0,0,0);   \
            accA = __builtin_amdgcn_mfma_f32_16x16x32_bf16(am, Bm0, accA, 0,0,0);   \
            accB = __builtin_amdgcn_mfma_f32_16x16x32_bf16(am, Bm1, accB, 0,0,0);   \
        }                                                                           \
    }                                                                               \
    asm volatile("s_waitcnt lgkmcnt(0)" ::: "memory");                              \
    __builtin_amdgcn_s_barrier();                                                   \
} while (0)

    for (int kt = 0; kt < 32; ++kt) {
        accA = zero; accB = zero;
        STEP(0, false, "4");
        // interleaved enc zero-fill: this kt's 32-code slab of 16 rows.
        // Row = lane>>2, floats [(lane&3)*4 + j*16]; hidden under compute.
        {
            float* zp = enc + (size_t)(row0 + wid * 16 + (lane >> 2)) * K_
                      + kt * 32 + (lane & 3) * 4;
            const f32x4 z4 = {0.f, 0.f, 0.f, 0.f};
            __builtin_nontemporal_store(z4, (f32x4*)zp);
            __builtin_nontemporal_store(z4, (f32x4*)(zp + 16));
        }
        STEP(1, kt == 31, "6");
        // fold: lane holds cols cA = kt*32+l15 (tile0), cB = cA+16 (tile1);
        // rows = kg*4 + r. Ascending k + strict < => first-occurrence.
        const int cA = kt * 32 + l15;
        const int cB = cA + 16;
        const float enA = En[cA], enB = En[cB];
#pragma unroll
        for (int r = 0; r < 4; ++r) {
            float dA = enA - 2.0f * accA[r];
            if (dA < best[r]) { best[r] = dA; bidx[r] = cA; }
            float dB = enB - 2.0f * accB[r];
            if (dB < best[r]) { best[r] = dB; bidx[r] = cB; }
        }
    }
#undef STEP

    // cross-lane argmin over the 16 cols + loss accumulation
    float wls = 0.f;   // valid at l15==0 lanes
#pragma unroll
    for (int r = 0; r < 4; ++r) {
        float v  = best[r];
        int   id = bidx[r];
#pragma unroll
        for (int m = 1; m < 16; m <<= 1) {
            float ov = __shfl_xor(v, m);
            int   oi = __shfl_xor(id, m);
            if (ov < v || (ov == v && oi < id)) { v = ov; id = oi; }
        }
        if (l15 == 0) {
            int rr = kg * 4 + r;
            atomicAdd(&counts[id], 1);
            widx[wid][rr] = id;             // wave-local broadcast via LDS
            wls += v + xn[wid][rr];         // row loss = ||x||^2 + min dist
        }
    }
    // fold wave loss across the 4 kg-leader lanes (0,16,32,48)
    wls += __shfl_xor(wls, 16);
    wls += __shfl_xor(wls, 32);
    if (lane == 0) partials[blockIdx.x * 4 + wid] = wls;

    asm volatile("s_waitcnt lgkmcnt(0)" ::: "memory");   // widx visible in-wave
    asm volatile("s_waitcnt vmcnt(0)"  ::: "memory");    // all zero-writes retired

    // ---- scatter the 1.0s (one per row; same wave wrote that row's zeros)
    if (lane < 16) {
        float one = 1.0f;
        __builtin_nontemporal_store(
            one, enc + (size_t)(row0 + wid * 16 + lane) * K_ + widx[wid][lane]);
    }

    // ---- fused quantized write: out[b][c][hw] = emb[widx[r]][c].
    // lane = ci*16 + r: 4 channels x 16 contiguous hw = full 64B segments.
    {
        const int r  = l15;
        const int ci = kg;
        const int n0 = row0 + wid * 16;
        const int b  = n0 >> 12, hw = n0 & 4095;
        const int idv = widx[wid][r];
        const float* ep = emb + (size_t)idv * C_ + ci;
        float* op = outq + (size_t)b * (C_ * HW_) + (size_t)ci * HW_ + hw + r;
#pragma unroll
        for (int cb = 0; cb < 64; ++cb) {
            float qv = ep[cb * 4];
            __builtin_nontemporal_store(qv, op + (size_t)(cb * 4) * HW_);
        }
    }
}

// ----------------------------------------------------------------- finalize
__global__ __launch_bounds__(256) void k_final(const float* __restrict__ partials,
                                               const int* __restrict__ counts,
                                               float* __restrict__ out) {
    const int tid = threadIdx.x;
    float s = 0.f;
    for (int i = tid; i < 4096; i += 256) s += partials[i];
    float h = 0.f;
    for (int k = tid; k < K_; k += 256) {
        float p = (float)counts[k] * (1.0f / 65536.0f);
        h += p * logf(p + 1e-10f);
    }
    __shared__ float redS[4], redH[4];
#pragma unroll
    for (int o = 32; o > 0; o >>= 1) {
        s += __shfl_down(s, o);
        h += __shfl_down(h, o);
    }
    if ((tid & 63) == 0) { redS[tid >> 6] = s; redH[tid >> 6] = h; }
    __syncthreads();
    if (tid == 0) {
        float S = (redS[0] + redS[1]) + (redS[2] + redS[3]);
        float H = (redH[0] + redH[1]) + (redH[2] + redH[3]);
        out[0]        = 0.25f * S / 16777216.0f;
        out[OUT_POFF] = expf(-H);
    }
}

extern "C" void kernel_launch(void* const* d_in, const int* in_sizes, int n_in,
                              void* d_out, int out_size, void* d_ws, size_t ws_size,
                              hipStream_t stream) {
    const float* x   = (const float*)d_in[0];
    const float* emb = (const float*)d_in[1];
    float* out = (float*)d_out;
    char*  ws  = (char*)d_ws;

    // Workspace layout
    int*   counts   = (int*)(ws + 262144);        //   4096 B
    float* partials = (float*)(ws + 266240);      //  16384 B
    float* enorm    = (float*)(ws + 282624);      //   4096 B
    char*  epk      = ws + 286720;                // 1048576 B packed e-splits (2-way)

    k_prep       <<<K_,      256, 0, stream>>>(emb, epk, enorm, counts);
    k_argmin_mfma<<<N_ / 64, 256, 0, stream>>>(x, epk, enorm, emb, counts,
                                               out + OUT_EOFF, out + OUT_QOFF,
                                               partials);
    k_final      <<<1,       256, 0, stream>>>(partials, counts, out);
}

// Round 16
// 251.837 us; speedup vs baseline: 1.6878x; 1.6878x over previous
//
#include <hip/hip_runtime.h>
#include <cfloat>

// Problem constants
#define B_   16
#define C_   256
#define HW_  4096      // 64*64
#define N_   65536     // B_*HW_
#define K_   1024

// Output layout (float32, concatenated flat in return order):
//  [0] loss | [1,+16777216) quantized (b c h w) | [16777217] perplexity
//  [16777218,+67108864) encodings (N,K)
#define OUT_QOFF   1
#define OUT_POFF   16777217
#define OUT_EOFF   16777218

typedef __bf16 bf16x8 __attribute__((ext_vector_type(8)));
typedef float  f32x4  __attribute__((ext_vector_type(4)));

// ---------------------------------------------------------------- bf16 split
__device__ inline ushort f2bf(float f) {
    union { float f; unsigned u; } a; a.f = f;
    unsigned u = a.u;
    unsigned r = (u + 0x7fffu + ((u >> 16) & 1u)) >> 16;   // RNE
    return (ushort)r;
}
__device__ inline float bf2f(ushort u) {
    union { float f; unsigned u; } a; a.u = ((unsigned)u) << 16; return a.f;
}

// ------------------------------------- prep: pack e (2-split) + enorm + cnt0
// One block per code k; thread c handles channel c.
// Packed layout per step s in [0,64): s = (k>>5)*2 + (c>>7); within 16384-B
// block: [split(2)][cg(16)][code(32)][ci(8)] bf16.
__global__ __launch_bounds__(256) void k_prep(const float* __restrict__ emb,
                                              char* __restrict__ epk,
                                              float* __restrict__ enorm,
                                              int* __restrict__ counts) {
    const int k = blockIdx.x;
    const int c = threadIdx.x;
    float v = emb[k * C_ + c];
    ushort h = f2bf(v);
    ushort m = f2bf(v - bf2f(h));
    int s  = (k >> 5) * 2 + (c >> 7);
    int cl = c & 127;
    size_t off = (size_t)s * 16384 + (size_t)((cl >> 3) * 512 + (k & 31) * 16 + (cl & 7) * 2);
    *(ushort*)(epk + off)        = h;
    *(ushort*)(epk + off + 8192) = m;
    float sq = v * v;
    __shared__ float red[4];
#pragma unroll
    for (int o = 32; o > 0; o >>= 1) sq += __shfl_down(sq, o);
    if ((c & 63) == 0) red[c >> 6] = sq;
    __syncthreads();
    if (c == 0) {
        enorm[k]  = (red[0] + red[1]) + (red[2] + red[3]);
        counts[k] = 0;
    }
}

// ------- MFMA argmin GEMM (waves 0-3) + dedicated writer wave (wave 4)
// Waves 0-3: 64 rows x 1024 codes GEMM, R14 structure unchanged (4-product
// fp32 emulation, 2-split A in regs, 2-split B LDS double buffer, counted
// vmcnt). Wave 4: streams the block's 256KB of enc ZEROS during the main
// loop on its OWN vmcnt (stores never couple into the GEMM waves' counted
// waits -- the R15 failure), pacing through the same barrier sequence
// (1 + 128 + 1 per wave). Epilogue: wave 4 scatters the 64 ones; waves 0-3
// write quantized = gathered emb rows; loss = ||x||^2 + best distance.
__global__ __launch_bounds__(320, 5) void k_argmin_mfma(const float* __restrict__ x,
                                                        const char* __restrict__ epk,
                                                        const float* __restrict__ enorm,
                                                        const float* __restrict__ emb,
                                                        int* __restrict__ counts,
                                                        float* __restrict__ enc,
                                                        float* __restrict__ outq,
                                                        float* __restrict__ partials) {
    __shared__ __align__(16) char Bs[2][16384];
    __shared__ float En[K_];
    __shared__ int   widx[4][16];
    __shared__ float xn[4][16];

    const int tid  = threadIdx.x;
    const int lane = tid & 63;
    const int wid  = tid >> 6;           // 0..3 GEMM, 4 writer
    const int l15  = lane & 15;
    const int kg   = lane >> 4;
    const int row0 = blockIdx.x * 64;
    const int cpOff = wid * 1024 + lane * 16;   // GEMM wave's copy offset

    for (int i = tid; i < K_; i += 320) En[i] = enorm[i];

    // ---- A fragments (GEMM waves): row = row0 + wid*16 + l15, k = kg*8+i.
    union FU { bf16x8 v; ushort u[8]; };
    FU Ah[8], Am[8];
    if (wid < 4) {
        const int n  = row0 + wid * 16 + l15;
        const int b  = n >> 12, hw = n & 4095;
        const float* xb = x + (size_t)b * (C_ * HW_) + hw;
        float xs = 0.f;
#pragma unroll
        for (int cb = 0; cb < 8; ++cb) {
#pragma unroll
            for (int i = 0; i < 8; ++i) {
                float v = xb[(cb * 32 + kg * 8 + i) * HW_];
                xs += v * v;
                ushort h = f2bf(v);
                Ah[cb].u[i] = h;
                Am[cb].u[i] = f2bf(v - bf2f(h));
            }
        }
        xs += __shfl_xor(xs, 16);
        xs += __shfl_xor(xs, 32);          // all kg lanes: full row sum
        if (kg == 0) xn[wid][l15] = xs;
    }
    __syncthreads();                       // barrier #1 (all 5 waves)

    if (wid < 4) {
        // =========================== GEMM path ===========================
        {
            const char* src = epk + (size_t)cpOff;
            char* dstb = &Bs[0][0] + cpOff;
#pragma unroll
            for (int j = 0; j < 4; ++j) {
                __builtin_amdgcn_global_load_lds(
                    (const __attribute__((address_space(1))) void*)(src + j * 4096),
                    (__attribute__((address_space(3))) void*)(dstb + j * 4096), 16, 0, 0);
            }
        }

        float best[4] = {FLT_MAX, FLT_MAX, FLT_MAX, FLT_MAX};
        int   bidx[4] = {0, 0, 0, 0};
        const int laneB = kg * 512 + l15 * 16;
        const f32x4 zero = {0.f, 0.f, 0.f, 0.f};
        f32x4 accA, accB;

#define STEP(H, IS_LAST) do {                                                       \
    if (!(IS_LAST)) {                                                               \
        int sn = 2 * kt + (H) + 1;                                                  \
        const char* src = epk + (size_t)sn * 16384 + (size_t)cpOff;                 \
        char* dstb = &Bs[1 - (H)][0] + cpOff;                                       \
        _Pragma("unroll")                                                           \
        for (int j = 0; j < 4; ++j) {                                               \
            __builtin_amdgcn_global_load_lds(                                       \
                (const __attribute__((address_space(1))) void*)(src + j * 4096),    \
                (__attribute__((address_space(3))) void*)(dstb + j * 4096),         \
                16, 0, 0);                                                          \
        }                                                                           \
        asm volatile("s_waitcnt vmcnt(4)" ::: "memory");                            \
    } else {                                                                        \
        asm volatile("s_waitcnt vmcnt(0)" ::: "memory");                            \
    }                                                                               \
    __builtin_amdgcn_s_barrier();                                                   \
    asm volatile("" ::: "memory");                                                  \
    {                                                                               \
        const char* bbase = &Bs[(H)][0] + laneB;                                    \
        _Pragma("unroll")                                                           \
        for (int cbl = 0; cbl < 4; ++cbl) {                                         \
            const char* bp = bbase + cbl * 2048;                                    \
            bf16x8 Bh0 = *(const bf16x8*)(bp);                                      \
            bf16x8 Bm0 = *(const bf16x8*)(bp + 8192);                               \
            bf16x8 Bh1 = *(const bf16x8*)(bp + 256);                                \
            bf16x8 Bm1 = *(const bf16x8*)(bp + 8448);                               \
            const bf16x8 ah = Ah[(H) * 4 + cbl].v;                                  \
            const bf16x8 am = Am[(H) * 4 + cbl].v;                                  \
            accA = __builtin_amdgcn_mfma_f32_16x16x32_bf16(ah, Bh0, accA, 0,0,0);   \
            accB = __builtin_amdgcn_mfma_f32_16x16x32_bf16(ah, Bh1, accB, 0,0,0);   \
            accA = __builtin_amdgcn_mfma_f32_16x16x32_bf16(am, Bh0, accA, 0,0,0);   \
            accB = __builtin_amdgcn_mfma_f32_16x16x32_bf16(am, Bh1, accB, 0,0,0);   \
            accA = __builtin_amdgcn_mfma_f32_16x16x32_bf16(ah, Bm0, accA, 0,0,0);   \
            accB = __builtin_amdgcn_mfma_f32_16x16x32_bf16(ah, Bm1, accB, 0,0,0);   \
            accA = __builtin_amdgcn_mfma_f32_16x16x32_bf16(am, Bm0, accA, 0,0,0);   \
            accB = __builtin_amdgcn_mfma_f32_16x16x32_bf16(am, Bm1, accB, 0,0,0);   \
        }                                                                           \
    }                                                                               \
    asm volatile("s_waitcnt lgkmcnt(0)" ::: "memory");                              \
    __builtin_amdgcn_s_barrier();                                                   \
} while (0)

        for (int kt = 0; kt < 32; ++kt) {
            accA = zero; accB = zero;
            STEP(0, false);
            STEP(1, kt == 31);
            const int cA = kt * 32 + l15;
            const int cB = cA + 16;
            const float enA = En[cA], enB = En[cB];
#pragma unroll
            for (int r = 0; r < 4; ++r) {
                float dA = enA - 2.0f * accA[r];
                if (dA < best[r]) { best[r] = dA; bidx[r] = cA; }
                float dB = enB - 2.0f * accB[r];
                if (dB < best[r]) { best[r] = dB; bidx[r] = cB; }
            }
        }
#undef STEP

        // cross-lane argmin + loss accumulation
        float wls = 0.f;
#pragma unroll
        for (int r = 0; r < 4; ++r) {
            float v  = best[r];
            int   id = bidx[r];
#pragma unroll
            for (int m = 1; m < 16; m <<= 1) {
                float ov = __shfl_xor(v, m);
                int   oi = __shfl_xor(id, m);
                if (ov < v || (ov == v && oi < id)) { v = ov; id = oi; }
            }
            if (l15 == 0) {
                int rr = kg * 4 + r;
                atomicAdd(&counts[id], 1);
                widx[wid][rr] = id;
                wls += v + xn[wid][rr];     // row loss = ||x||^2 + min dist
            }
        }
        wls += __shfl_xor(wls, 16);
        wls += __shfl_xor(wls, 32);
        if (lane == 0) partials[blockIdx.x * 4 + wid] = wls;
    } else {
        // ========================== writer path ==========================
        // Zero this block's 64 enc rows (256KB) on wave 4's private vmcnt,
        // pacing through the GEMM waves' 128 in-loop barriers (4 per kt).
        const f32x4 z4 = {0.f, 0.f, 0.f, 0.f};
        for (int kt = 0; kt < 32; ++kt) {
            // rows 2kt, 2kt+1; 4 chunks of 1KB each per row
            float* r0 = enc + (size_t)(row0 + kt * 2)     * K_ + lane * 4;
            float* r1 = enc + (size_t)(row0 + kt * 2 + 1) * K_ + lane * 4;
#pragma unroll
            for (int h = 0; h < 4; ++h) {
                __builtin_amdgcn_s_barrier();
                __builtin_nontemporal_store(z4, (f32x4*)(r0 + h * 256));
                __builtin_nontemporal_store(z4, (f32x4*)(r1 + h * 256));
            }
        }
    }

    __syncthreads();   // widx ready; writer's zero-stores drained (own wave)

    if (wid == 4) {
        // scatter the 64 ones (zeros already retired by this wave's sync)
        const int* wf = &widx[0][0];
        float one = 1.0f;
        __builtin_nontemporal_store(
            one, enc + (size_t)(row0 + lane) * K_ + wf[lane]);
    } else {
        // fused quantized write: out[b][c][hw] = emb[widx[r]][c].
        // lane = ci*16 + r: 4 channels x 16 contiguous hw = 64B segments.
        const int r  = l15;
        const int ci = kg;
        const int n0 = row0 + wid * 16;
        const int b  = n0 >> 12, hw = n0 & 4095;
        const int idv = widx[wid][r];
        const float* ep = emb + (size_t)idv * C_ + ci;
        float* op = outq + (size_t)b * (C_ * HW_) + (size_t)ci * HW_ + hw + r;
#pragma unroll
        for (int cb = 0; cb < 64; ++cb) {
            float qv = ep[cb * 4];
            __builtin_nontemporal_store(qv, op + (size_t)(cb * 4) * HW_);
        }
    }
}

// ----------------------------------------------------------------- finalize
__global__ __launch_bounds__(256) void k_final(const float* __restrict__ partials,
                                               const int* __restrict__ counts,
                                               float* __restrict__ out) {
    const int tid = threadIdx.x;
    float s = 0.f;
    for (int i = tid; i < 4096; i += 256) s += partials[i];
    float h = 0.f;
    for (int k = tid; k < K_; k += 256) {
        float p = (float)counts[k] * (1.0f / 65536.0f);
        h += p * logf(p + 1e-10f);
    }
    __shared__ float redS[4], redH[4];
#pragma unroll
    for (int o = 32; o > 0; o >>= 1) {
        s += __shfl_down(s, o);
        h += __shfl_down(h, o);
    }
    if ((tid & 63) == 0) { redS[tid >> 6] = s; redH[tid >> 6] = h; }
    __syncthreads();
    if (tid == 0) {
        float S = (redS[0] + redS[1]) + (redS[2] + redS[3]);
        float H = (redH[0] + redH[1]) + (redH[2] + redH[3]);
        out[0]        = 0.25f * S / 16777216.0f;
        out[OUT_POFF] = expf(-H);
    }
}

extern "C" void kernel_launch(void* const* d_in, const int* in_sizes, int n_in,
                              void* d_out, int out_size, void* d_ws, size_t ws_size,
                              hipStream_t stream) {
    const float* x   = (const float*)d_in[0];
    const float* emb = (const float*)d_in[1];
    float* out = (float*)d_out;
    char*  ws  = (char*)d_ws;

    // Workspace layout
    int*   counts   = (int*)(ws + 262144);        //   4096 B
    float* partials = (float*)(ws + 266240);      //  16384 B
    float* enorm    = (float*)(ws + 282624);      //   4096 B
    char*  epk      = ws + 286720;                // 1048576 B packed e-splits (2-way)

    k_prep       <<<K_,      256, 0, stream>>>(emb, epk, enorm, counts);
    k_argmin_mfma<<<N_ / 64, 320, 0, stream>>>(x, epk, enorm, emb, counts,
                                               out + OUT_EOFF, out + OUT_QOFF,
                                               partials);
    k_final      <<<1,       256, 0, stream>>>(partials, counts, out);
}

// Round 17
// 183.382 us; speedup vs baseline: 2.3179x; 1.3733x over previous
//
#include <hip/hip_runtime.h>
#include <cfloat>

// Problem constants
#define B_   16
#define C_   256
#define HW_  4096      // 64*64
#define N_   65536     // B_*HW_
#define K_   1024

// Output layout (float32, concatenated flat in return order):
//  [0] loss | [1,+16777216) quantized (b c h w) | [16777217] perplexity
//  [16777218,+67108864) encodings (N,K)
#define OUT_QOFF   1
#define OUT_POFF   16777217
#define OUT_EOFF   16777218

typedef __bf16 bf16x8 __attribute__((ext_vector_type(8)));
typedef float  f32x4  __attribute__((ext_vector_type(4)));

// ---------------------------------------------------------------- bf16 split
__device__ inline ushort f2bf(float f) {
    union { float f; unsigned u; } a; a.f = f;
    unsigned u = a.u;
    unsigned r = (u + 0x7fffu + ((u >> 16) & 1u)) >> 16;   // RNE
    return (ushort)r;
}
__device__ inline float bf2f(ushort u) {
    union { float f; unsigned u; } a; a.u = ((unsigned)u) << 16; return a.f;
}

// ------------------------------------- prep: pack e (2-split) + enorm + cnt0
// One block per code k; thread c handles channel c.
// Packed layout per step s in [0,64): s = (k>>5)*2 + (c>>7); within 16384-B
// block: [split(2)][cg(16)][code(32)][ci(8)] bf16.
__global__ __launch_bounds__(256) void k_prep(const float* __restrict__ emb,
                                              char* __restrict__ epk,
                                              float* __restrict__ enorm,
                                              int* __restrict__ counts) {
    const int k = blockIdx.x;
    const int c = threadIdx.x;
    float v = emb[k * C_ + c];
    ushort h = f2bf(v);
    ushort m = f2bf(v - bf2f(h));
    int s  = (k >> 5) * 2 + (c >> 7);
    int cl = c & 127;
    size_t off = (size_t)s * 16384 + (size_t)((cl >> 3) * 512 + (k & 31) * 16 + (cl & 7) * 2);
    *(ushort*)(epk + off)        = h;
    *(ushort*)(epk + off + 8192) = m;
    float sq = v * v;
    __shared__ float red[4];
#pragma unroll
    for (int o = 32; o > 0; o >>= 1) sq += __shfl_down(sq, o);
    if ((c & 63) == 0) red[c >> 6] = sq;
    __syncthreads();
    if (c == 0) {
        enorm[k]  = (red[0] + red[1]) + (red[2] + red[3]);
        counts[k] = 0;
    }
}

// ---------- MFMA argmin GEMM + in-loop enc zero-fill + fused epilogue
// Block: 64 rows x 1024 codes, 4 waves (16 rows each). R14 GEMM structure.
// Per kt, after STEP1's staging loads, each thread issues 2 NT zero-stores
// covering enc rows {2kt, 2kt+1} of this block. vmcnt renumbering (stores
// are NEWER than the loads each wait needs): STEP0 = vmcnt(6) [kt=0: 4],
// STEP1 = vmcnt(6); stores forced to retire only ~1.5 steps after issue.
// Epilogue: scatter ones, quantized = gathered emb row, loss = ||x||^2+dist.
__global__ __launch_bounds__(256, 4) void k_argmin_mfma(const float* __restrict__ x,
                                                        const char* __restrict__ epk,
                                                        const float* __restrict__ enorm,
                                                        const float* __restrict__ emb,
                                                        int* __restrict__ counts,
                                                        float* __restrict__ enc,
                                                        float* __restrict__ outq,
                                                        float* __restrict__ partials) {
    __shared__ __align__(16) char Bs[2][16384];
    __shared__ float En[K_];
    __shared__ int   widx[4][16];
    __shared__ float xn[4][16];

    const int tid  = threadIdx.x;
    const int lane = tid & 63;
    const int wid  = tid >> 6;
    const int l15  = lane & 15;
    const int kg   = lane >> 4;
    const int row0 = blockIdx.x * 64;
    const int cpOff = wid * 1024 + lane * 16;   // wave's copy offset (4KB/wave)

    for (int i = tid; i < K_; i += 256) En[i] = enorm[i];

    // ---- A fragments: row = row0 + wid*16 + l15, k-elems = kg*8+i.
    //      Also accumulate ||x_row||^2 (fp32) and park it in LDS.
    union FU { bf16x8 v; ushort u[8]; };
    FU Ah[8], Am[8];
    {
        const int n  = row0 + wid * 16 + l15;
        const int b  = n >> 12, hw = n & 4095;
        const float* xb = x + (size_t)b * (C_ * HW_) + hw;
        float xs = 0.f;
#pragma unroll
        for (int cb = 0; cb < 8; ++cb) {
#pragma unroll
            for (int i = 0; i < 8; ++i) {
                float v = xb[(cb * 32 + kg * 8 + i) * HW_];
                xs += v * v;
                ushort h = f2bf(v);
                Ah[cb].u[i] = h;
                Am[cb].u[i] = f2bf(v - bf2f(h));
            }
        }
        xs += __shfl_xor(xs, 16);
        xs += __shfl_xor(xs, 32);          // all kg lanes: full row sum
        if (kg == 0) xn[wid][l15] = xs;
    }
    __syncthreads();   // drains vmcnt+lgkmcnt: clean slate for counting

    // ---- stage step 0 (src and dst share the same offset: cpOff+j*4096)
    {
        const char* src = epk + (size_t)cpOff;
        char* dstb = &Bs[0][0] + cpOff;
#pragma unroll
        for (int j = 0; j < 4; ++j) {
            __builtin_amdgcn_global_load_lds(
                (const __attribute__((address_space(1))) void*)(src + j * 4096),
                (__attribute__((address_space(3))) void*)(dstb + j * 4096), 16, 0, 0);
        }
    }

    float best[4] = {FLT_MAX, FLT_MAX, FLT_MAX, FLT_MAX};
    int   bidx[4] = {0, 0, 0, 0};
    const int laneB = kg * 512 + l15 * 16;
    const f32x4 zero = {0.f, 0.f, 0.f, 0.f};
    f32x4 accA, accB;
    // zero-fill base: thread covers row (tid>>7), floats [(tid&127)*8, +8)
    float* const encz = enc + (size_t)(row0 + (tid >> 7)) * K_ + (tid & 127) * 8;

#define STEP(H, IS_LAST, VMS, DOSTORE) do {                                         \
    if (!(IS_LAST)) {                                                               \
        int sn = 2 * kt + (H) + 1;                                                  \
        const char* src = epk + (size_t)sn * 16384 + (size_t)cpOff;                 \
        char* dstb = &Bs[1 - (H)][0] + cpOff;                                       \
        _Pragma("unroll")                                                           \
        for (int j = 0; j < 4; ++j) {                                               \
            __builtin_amdgcn_global_load_lds(                                       \
                (const __attribute__((address_space(1))) void*)(src + j * 4096),    \
                (__attribute__((address_space(3))) void*)(dstb + j * 4096),         \
                16, 0, 0);                                                          \
        }                                                                           \
    }                                                                               \
    if (DOSTORE) {                                                                  \
        float* zp = encz + (size_t)(2 * kt) * K_;                                   \
        const f32x4 z4 = {0.f, 0.f, 0.f, 0.f};                                      \
        __builtin_nontemporal_store(z4, (f32x4*)zp);                                \
        __builtin_nontemporal_store(z4, (f32x4*)(zp + 4));                          \
    }                                                                               \
    asm volatile("s_waitcnt vmcnt(" VMS ")" ::: "memory");                          \
    __builtin_amdgcn_s_barrier();                                                   \
    asm volatile("" ::: "memory");                                                  \
    {                                                                               \
        const char* bbase = &Bs[(H)][0] + laneB;                                    \
        _Pragma("unroll")                                                           \
        for (int cbl = 0; cbl < 4; ++cbl) {                                         \
            const char* bp = bbase + cbl * 2048;                                    \
            bf16x8 Bh0 = *(const bf16x8*)(bp);                                      \
            bf16x8 Bm0 = *(const bf16x8*)(bp + 8192);                               \
            bf16x8 Bh1 = *(const bf16x8*)(bp + 256);                                \
            bf16x8 Bm1 = *(const bf16x8*)(bp + 8448);                               \
            const bf16x8 ah = Ah[(H) * 4 + cbl].v;                                  \
            const bf16x8 am = Am[(H) * 4 + cbl].v;                                  \
            accA = __builtin_amdgcn_mfma_f32_16x16x32_bf16(ah, Bh0, accA, 0,0,0);   \
            accB = __builtin_amdgcn_mfma_f32_16x16x32_bf16(ah, Bh1, accB, 0,0,0);   \
            accA = __builtin_amdgcn_mfma_f32_16x16x32_bf16(am, Bh0, accA, 0,0,0);   \
            accB = __builtin_amdgcn_mfma_f32_16x16x32_bf16(am, Bh1, accB, 0,0,0);   \
            accA = __builtin_amdgcn_mfma_f32_16x16x32_bf16(ah, Bm0, accA, 0,0,0);   \
            accB = __builtin_amdgcn_mfma_f32_16x16x32_bf16(ah, Bm1, accB, 0,0,0);   \
            accA = __builtin_amdgcn_mfma_f32_16x16x32_bf16(am, Bm0, accA, 0,0,0);   \
            accB = __builtin_amdgcn_mfma_f32_16x16x32_bf16(am, Bm1, accB, 0,0,0);   \
        }                                                                           \
    }                                                                               \
    asm volatile("s_waitcnt lgkmcnt(0)" ::: "memory");                              \
    __builtin_amdgcn_s_barrier();                                                   \
} while (0)

    for (int kt = 0; kt < 32; ++kt) {
        accA = zero; accB = zero;
        if (kt == 0) { STEP(0, false, "4", false); }
        else         { STEP(0, false, "6", false); }
        if (kt == 31) { STEP(1, true,  "0", true); }
        else          { STEP(1, false, "6", true); }
        // fold: lane holds cols cA = kt*32+l15 (tile0), cB = cA+16 (tile1);
        // rows = kg*4 + r. Ascending k + strict < => first-occurrence.
        const int cA = kt * 32 + l15;
        const int cB = cA + 16;
        const float enA = En[cA], enB = En[cB];
#pragma unroll
        for (int r = 0; r < 4; ++r) {
            float dA = enA - 2.0f * accA[r];
            if (dA < best[r]) { best[r] = dA; bidx[r] = cA; }
            float dB = enB - 2.0f * accB[r];
            if (dB < best[r]) { best[r] = dB; bidx[r] = cB; }
        }
    }
#undef STEP

    // cross-lane argmin over the 16 cols + loss accumulation
    float wls = 0.f;   // valid at l15==0 lanes
#pragma unroll
    for (int r = 0; r < 4; ++r) {
        float v  = best[r];
        int   id = bidx[r];
#pragma unroll
        for (int m = 1; m < 16; m <<= 1) {
            float ov = __shfl_xor(v, m);
            int   oi = __shfl_xor(id, m);
            if (ov < v || (ov == v && oi < id)) { v = ov; id = oi; }
        }
        if (l15 == 0) {
            int rr = kg * 4 + r;
            atomicAdd(&counts[id], 1);
            widx[wid][rr] = id;             // wave-local broadcast via LDS
            wls += v + xn[wid][rr];         // row loss = ||x||^2 + min dist
        }
    }
    // fold wave loss across the 4 kg-leader lanes (0,16,32,48)
    wls += __shfl_xor(wls, 16);
    wls += __shfl_xor(wls, 32);
    if (lane == 0) partials[blockIdx.x * 4 + wid] = wls;

    __syncthreads();   // widx visible; every wave's zero-stores retired

    // ---- scatter the 1.0s (zeros for these rows are globally visible)
    if (lane < 16) {
        float one = 1.0f;
        __builtin_nontemporal_store(
            one, enc + (size_t)(row0 + wid * 16 + lane) * K_ + widx[wid][lane]);
    }

    // ---- fused quantized write: out[b][c][hw] = emb[widx[r]][c].
    // lane = ci*16 + r: 4 channels x 16 contiguous hw = full 64B segments.
    {
        const int r  = l15;
        const int ci = kg;
        const int n0 = row0 + wid * 16;
        const int b  = n0 >> 12, hw = n0 & 4095;
        const int idv = widx[wid][r];
        const float* ep = emb + (size_t)idv * C_ + ci;
        float* op = outq + (size_t)b * (C_ * HW_) + (size_t)ci * HW_ + hw + r;
#pragma unroll
        for (int cb = 0; cb < 64; ++cb) {
            float qv = ep[cb * 4];
            __builtin_nontemporal_store(qv, op + (size_t)(cb * 4) * HW_);
        }
    }
}

// ----------------------------------------------------------------- finalize
__global__ __launch_bounds__(256) void k_final(const float* __restrict__ partials,
                                               const int* __restrict__ counts,
                                               float* __restrict__ out) {
    const int tid = threadIdx.x;
    float s = 0.f;
    for (int i = tid; i < 4096; i += 256) s += partials[i];
    float h = 0.f;
    for (int k = tid; k < K_; k += 256) {
        float p = (float)counts[k] * (1.0f / 65536.0f);
        h += p * logf(p + 1e-10f);
    }
    __shared__ float redS[4], redH[4];
#pragma unroll
    for (int o = 32; o > 0; o >>= 1) {
        s += __shfl_down(s, o);
        h += __shfl_down(h, o);
    }
    if ((tid & 63) == 0) { redS[tid >> 6] = s; redH[tid >> 6] = h; }
    __syncthreads();
    if (tid == 0) {
        float S = (redS[0] + redS[1]) + (redS[2] + redS[3]);
        float H = (redH[0] + redH[1]) + (redH[2] + redH[3]);
        out[0]        = 0.25f * S / 16777216.0f;
        out[OUT_POFF] = expf(-H);
    }
}

extern "C" void kernel_launch(void* const* d_in, const int* in_sizes, int n_in,
                              void* d_out, int out_size, void* d_ws, size_t ws_size,
                              hipStream_t stream) {
    const float* x   = (const float*)d_in[0];
    const float* emb = (const float*)d_in[1];
    float* out = (float*)d_out;
    char*  ws  = (char*)d_ws;

    // Workspace layout
    int*   counts   = (int*)(ws + 262144);        //   4096 B
    float* partials = (float*)(ws + 266240);      //  16384 B
    float* enorm    = (float*)(ws + 282624);      //   4096 B
    char*  epk      = ws + 286720;                // 1048576 B packed e-splits (2-way)

    k_prep       <<<K_,      256, 0, stream>>>(emb, epk, enorm, counts);
    k_argmin_mfma<<<N_ / 64, 256, 0, stream>>>(x, epk, enorm, emb, counts,
                                               out + OUT_EOFF, out + OUT_QOFF,
                                               partials);
    k_final      <<<1,       256, 0, stream>>>(partials, counts, out);
}